// Round 1
// baseline (161.218 us; speedup 1.0000x reference)
//
#include <hip/hip_runtime.h>

// S4D: y[b,h,l] = relu( causal_conv(k[h], x[b,h])[l] )
//   k[h,m] = 2*Re sum_n Ceff[h,n] * w[h,n]^m
// implemented as diagonal complex SSM scan:
//   s_n[l] = w_n * s_n[l-1] + x[l];  y[l] = 2*Re sum_n Ceff_n * s_n[l]
//
// Mapping: one wave (64 lanes) per (b,h) sequence; lane n owns state n.
// Per 64-step chunk: shfl-broadcast x, per-lane contribution -> LDS[t*65+n]
// (stride 65 => conflict-free writes and transposed reads), then lane j
// reduces row j and stores relu(y) coalesced.

#define BATCH_ 8
#define H_ 256
#define N_ 64
#define L_ 2048

__global__ __launch_bounds__(64) void s4d_scan_kernel(
    const float* __restrict__ x,       // (B, H, L)
    const float* __restrict__ A_real,  // (H, N)
    const float* __restrict__ A_imag,  // (H, N)
    const float* __restrict__ Bmat,    // (1, H, N, 2)
    const float* __restrict__ Cmat,    // (1, H, N, 2)
    const float* __restrict__ inv_dt,  // (H, 1)
    float* __restrict__ out)           // (B, 1, H, L)
{
    __shared__ float lds[64 * 65];

    const int seq = blockIdx.x;        // b*H + h
    const int h   = seq & (H_ - 1);
    const int n   = threadIdx.x;       // 0..63 : state index

    // ---- per-(h,n) parameter setup (once per wave) ----
    const int hn = h * N_ + n;
    const float ar = A_real[hn];
    const float ai = A_imag[hn];
    const float Ar = -expf(ar);        // A = -exp(A_real) - i*A_imag
    const float Ai = -ai;
    const float dtv = expf(inv_dt[h]);
    const float dr = dtv * Ar;
    const float di = dtv * Ai;
    // w = exp(dtA)
    const float ew = expf(dr);
    float sdi, cdi;
    sincosf(di, &sdi, &cdi);
    const float wr = ew * cdi;
    const float wi = ew * sdi;
    // t = (exp(dtA) - 1) / A   (complex divide by A)
    const float em1r = wr - 1.0f;
    const float em1i = wi;
    const float invden = 1.0f / (Ar * Ar + Ai * Ai);
    const float tr = (em1r * Ar + em1i * Ai) * invden;
    const float ti = (em1i * Ar - em1r * Ai) * invden;
    // bc = B*C (complex)
    const float br = Bmat[2 * hn], bi = Bmat[2 * hn + 1];
    const float cr = Cmat[2 * hn], ci = Cmat[2 * hn + 1];
    const float bcr = br * cr - bi * ci;
    const float bci = br * ci + bi * cr;
    // Ceff = 2 * bc * t   (fold the 2*Re(...) factor in here)
    const float Cr = 2.0f * (bcr * tr - bci * ti);
    const float Ci = 2.0f * (bcr * ti + bci * tr);

    const float* xp = x   + (size_t)seq * L_;
    float*       yp = out + (size_t)seq * L_;

    float sr = 0.0f, si = 0.0f;

    for (int l0 = 0; l0 < L_; l0 += 64) {
        const float xv = xp[l0 + n];   // coalesced chunk load, one value/lane

        #pragma unroll
        for (int t = 0; t < 64; ++t) {
            const float xt = __shfl(xv, t);            // broadcast x[l0+t]
            const float nsr = fmaf(sr, wr, fmaf(si, -wi, xt));
            const float nsi = fmaf(sr, wi, si * wr);
            sr = nsr;
            si = nsi;
            lds[t * 65 + n] = fmaf(Cr, sr, -(Ci * si)); // Re(Ceff * s)
        }
        __syncthreads();

        // lane j reduces row j: y[l0+j] = sum_n lds[j*65+n]
        const float* row = &lds[n * 65];
        float a0 = 0.f, a1 = 0.f, a2 = 0.f, a3 = 0.f;
        #pragma unroll
        for (int m = 0; m < 64; m += 4) {
            a0 += row[m + 0];
            a1 += row[m + 1];
            a2 += row[m + 2];
            a3 += row[m + 3];
        }
        const float y = (a0 + a1) + (a2 + a3);
        yp[l0 + n] = fmaxf(y, 0.0f);
        __syncthreads();
    }
}

extern "C" void kernel_launch(void* const* d_in, const int* in_sizes, int n_in,
                              void* d_out, int out_size, void* d_ws, size_t ws_size,
                              hipStream_t stream) {
    const float* x      = (const float*)d_in[0];
    const float* A_real = (const float*)d_in[1];
    const float* A_imag = (const float*)d_in[2];
    const float* Bmat   = (const float*)d_in[3];
    const float* Cmat   = (const float*)d_in[4];
    const float* inv_dt = (const float*)d_in[5];
    float* out = (float*)d_out;

    dim3 grid(BATCH_ * H_);
    dim3 block(64);
    s4d_scan_kernel<<<grid, block, 0, stream>>>(x, A_real, A_imag, Bmat, Cmat,
                                                inv_dt, out);
}